// Round 10
// baseline (181.153 us; speedup 1.0000x reference)
//
#include <hip/hip_runtime.h>
#include <stdint.h>

#define BATCH 32
#define HDIM 224
#define WDIM 224
#define CDIM 3
#define KTOT (HDIM * WDIM * CDIM)   // 150528
#define HID 64
#define KCHUNK 64
#define NBLK1 (KTOT / KCHUNK)       // 2352
#define PIX (HDIM * WDIM)           // 50176
#define BLK3 49                      // blocks per batch: 1024 thr * 1 px

#define NSHARD 16
#define BH (BATCH * HID)             // 2048
#define HACC_BYTES (NSHARD * BH * 4) // 128 KB
#define PART_BYTES ((size_t)NBLK1 * BH * 4)  // 19.3 MB

typedef float float4v __attribute__((ext_vector_type(4)));
// 4-byte-aligned vector loads (texel addresses are only 4B aligned)
typedef float float4u __attribute__((ext_vector_type(4), aligned(4)));
typedef float float2u __attribute__((ext_vector_type(2), aligned(4)));

// ---------------- Kernel 1: part[blk] = flat @ w1 slice (split-K) -----------
// Round-10: r8's 2-hid-per-lane algorithm, scalar-array codegen (hedge after
// two container failures on the r8 source; same semantics).
// Rationale (r7 counters): k1 is LDS-INSTRUCTION-THROUGHPUT bound -- 128
// broadcast ds_read_b128/wave feeding only 4 FMAs/lane; ~24 waves/CU share
// one LDS pipe (~11cyc/b128) ~= 25us serialized. With lane = (kh = k-half,
// hp = hid pair -> hids 2hp,2hp+1), each b128 x-read feeds 8 FMAs -> x-read
// count halves. w slice hoisted to regs; kh halves folded via shfl_xor(32).
// Staging stays r7's reg->ds_write path (loads feed pre-barrier ds_writes,
// so they cannot sink into the FMA loop -- the r0/r2 pathology).
__global__ __launch_bounds__(256, 4) void k1_gemm(const float* __restrict__ flat,
                                                  const float* __restrict__ w1,
                                                  float* __restrict__ hacc,
                                                  float* __restrict__ part) {
    __shared__ float smem[6144];                 // 24 KB
    const int tid  = threadIdx.x;
    const int lane = tid & 63;
    const int wave = tid >> 6;
    const int k0   = blockIdx.x * KCHUNK;

    // --- Issue all 6 global_load_dwordx4 per thread (pipelined) ---
    float4v rf0, rf1, rw0, rw1, rw2, rw3;
    {
        const int f0 = tid, f1 = tid + 256;      // flat float4 idx 0..511
        rf0 = *(const float4v*)(flat + (size_t)(f0 >> 4) * KTOT + k0 + (f0 & 15) * 4);
        rf1 = *(const float4v*)(flat + (size_t)(f1 >> 4) * KTOT + k0 + (f1 & 15) * 4);
        const float* wbase = w1 + (size_t)k0 * HID;
        rw0 = *(const float4v*)(wbase + (size_t)(tid +   0) * 4);
        rw1 = *(const float4v*)(wbase + (size_t)(tid + 256) * 4);
        rw2 = *(const float4v*)(wbase + (size_t)(tid + 512) * 4);
        rw3 = *(const float4v*)(wbase + (size_t)(tid + 768) * 4);
    }
    // --- ds_write as results land (compiler emits counted vmcnt) ---
    *(float4v*)(smem + (size_t)tid * 4)         = rf0;
    *(float4v*)(smem + (size_t)(tid + 256) * 4) = rf1;
    *(float4v*)(smem + 2048 + (size_t)(tid +   0) * 4) = rw0;
    *(float4v*)(smem + 2048 + (size_t)(tid + 256) * 4) = rw1;
    *(float4v*)(smem + 2048 + (size_t)(tid + 512) * 4) = rw2;
    *(float4v*)(smem + 2048 + (size_t)(tid + 768) * 4) = rw3;
    __syncthreads();

    const int kh    = lane >> 5;                 // k-half within wave's 16 k
    const int hp    = lane & 31;                 // hid pair -> hids 2hp, 2hp+1
    const int kbase = wave * 16 + kh * 8;        // 8 k's per lane

    // w slice LDS->regs: 8 x 2 scalar reads (adjacent words; compiler may
    // fuse to b64); halves differ by 512 words -> 2-way bank alias (free).
    float wx[8], wy[8];
#pragma unroll
    for (int i = 0; i < 8; ++i) {
        const int wof = 2048 + (kbase + i) * 64 + hp * 2;
        wx[i] = smem[wof];
        wy[i] = smem[wof + 1];
    }

    float accx[32], accy[32];
#pragma unroll
    for (int b = 0; b < 32; ++b) { accx[b] = 0.0f; accy[b] = 0.0f; }

    // Per kk-iter: 32 x-reads (b128, 2 broadcast groups) -> 8 FMAs each.
#pragma unroll
    for (int kk = 0; kk < 8; kk += 4) {
#pragma unroll
        for (int b = 0; b < 32; ++b) {
            const float4v x = *(const float4v*)(smem + b * 64 + kbase + kk);
            float ax = accx[b], ay = accy[b];
            ax = fmaf(x.x, wx[kk + 0], ax);  ay = fmaf(x.x, wy[kk + 0], ay);
            ax = fmaf(x.y, wx[kk + 1], ax);  ay = fmaf(x.y, wy[kk + 1], ay);
            ax = fmaf(x.z, wx[kk + 2], ax);  ay = fmaf(x.z, wy[kk + 2], ay);
            ax = fmaf(x.w, wx[kk + 3], ax);  ay = fmaf(x.w, wy[kk + 3], ay);
            accx[b] = ax; accy[b] = ay;
        }
    }

    // --- Fold the two kh halves: lanes l, l^32 hold the same (hp, b) ---
#pragma unroll
    for (int b = 0; b < 32; ++b) {
        accx[b] += __shfl_xor(accx[b], 32);
        accy[b] += __shfl_xor(accy[b], 32);
    }

    __syncthreads();                             // LDS tiles fully consumed
    // --- Waves 1..3 (kh==0 lanes) dump partials; wave 0 sums + stores ---
    if (wave && kh == 0) {
#pragma unroll
        for (int b = 0; b < 32; ++b) {
            const int dof = (wave - 1) * 2048 + b * 64 + hp * 2;
            smem[dof]     = accx[b];
            smem[dof + 1] = accy[b];
        }
    }
    __syncthreads();
    if (wave == 0 && kh == 0) {
        if (part) {                              // 2-stage: streaming store
            float* po = part + (size_t)blockIdx.x * BH;
#pragma unroll
            for (int b = 0; b < 32; ++b) {
                const int idx = b * 64 + hp * 2;
                po[idx]     = accx[b] + smem[idx]     + smem[2048 + idx]     + smem[4096 + idx];
                po[idx + 1] = accy[b] + smem[idx + 1] + smem[2048 + idx + 1] + smem[4096 + idx + 1];
            }
        } else {                                 // fallback: sharded atomics
            float* ha = hacc + (blockIdx.x & (NSHARD - 1)) * BH;
#pragma unroll
            for (int b = 0; b < 32; ++b) {
                const int idx = b * 64 + hp * 2;
                atomicAdd(ha + idx,
                          accx[b] + smem[idx] + smem[2048 + idx] + smem[4096 + idx]);
                atomicAdd(ha + idx + 1,
                          accy[b] + smem[idx + 1] + smem[2048 + idx + 1] + smem[4096 + idx + 1]);
            }
        }
    }
}

// -------- Kernel 2 (2-stage mode): reduce 2352 partials -> 16 shards --------
// r7 form VERBATIM: 512 blocks (2/CU), each owns shard slot hacc[q][b][*]
// (q<16, 147 rows each). Plain coalesced reads + plain store: zero atomics,
// zero memset. k3 sums the 16 shards.
__global__ __launch_bounds__(256) void k2_reduce(const float* __restrict__ part,
                                                 float* __restrict__ hacc) {
    const int b    = blockIdx.x >> 4;            // 0..31
    const int q    = blockIdx.x & 15;            // 0..15
    const int tid  = threadIdx.x;
    const int lane = tid & 63;
    const int wave = tid >> 6;
    const int r0   = q * 147;

    float s = 0.0f;
    for (int r = r0 + wave; r < r0 + 147; r += 4)
        s += part[(size_t)r * BH + b * HID + lane];

    __shared__ float red[3][64];
    if (wave) red[wave - 1][lane] = s;
    __syncthreads();
    if (wave == 0)
        hacc[q * BH + b * HID + lane] =
            s + red[0][lane] + red[1][lane] + red[2][lane];
}

// -------- Kernel 3: head + affine grid + bilinear sampling ------------------
// r4/r6/r7 form VERBATIM.
__global__ __launch_bounds__(1024) void k3_sample(const float* __restrict__ img,
                                                  const float* __restrict__ hacc,
                                                  const float* __restrict__ b1,
                                                  const float* __restrict__ w2,
                                                  const float* __restrict__ b2,
                                                  float* __restrict__ out) {
    const int b     = blockIdx.x / BLK3;
    const int strip = blockIdx.x - b * BLK3;
    const int tid   = threadIdx.x;
    const int lane  = tid & 63;

    __shared__ float sth[6];
    if (tid < 64) {                              // wave 0: lane = hid
        float a = 0.0f;
#pragma unroll
        for (int s = 0; s < NSHARD; ++s)
            a += hacc[s * BH + b * HID + lane];
        const float hv = tanhf(a + b1[lane]);
        const float* w2p = w2 + lane * 6;        // w2 is [HID][6] row-major
        float q[6];
#pragma unroll
        for (int t = 0; t < 6; ++t) q[t] = hv * w2p[t];
#pragma unroll
        for (int off = 32; off >= 1; off >>= 1) {
#pragma unroll
            for (int t = 0; t < 6; ++t) q[t] += __shfl_xor(q[t], off);
        }
        if (lane < 6) sth[lane] = tanhf(q[lane] + b2[lane]);
    }
    __syncthreads();

    const float t0 = sth[0], t1 = sth[1], t2 = sth[2];
    const float t3 = sth[3], t4 = sth[4], t5 = sth[5];

    const float* base = img + (size_t)b * KTOT;
    const int pix = strip * 1024 + tid;
    const int i   = pix / WDIM;
    const int j   = pix - i * WDIM;

    const float xt = (2.0f * (float)j - (float)(WDIM - 1)) / (float)(WDIM - 1);
    const float yt = (2.0f * (float)i - (float)(HDIM - 1)) / (float)(HDIM - 1);

    const float xs = t0 * xt + t1 * yt + t2;
    const float ys = t3 * xt + t4 * yt + t5;

    const float x = 0.5f * (xs + 1.0f) * (float)(WDIM - 1);
    const float y = 0.5f * (ys + 1.0f) * (float)(HDIM - 1);

    const int x0 = (int)floorf(x);
    const int y0 = (int)floorf(y);

    const int x0c = min(max(x0, 0), WDIM - 1);
    const int x1c = min(max(x0 + 1, 0), WDIM - 1);
    const int y0c = min(max(y0, 0), HDIM - 1);
    const int y1c = min(max(y0 + 1, 0), HDIM - 1);

    // Reference computes weights from CLIPPED corner coordinates.
    const float x0f = (float)x0c, x1f = (float)x1c;
    const float y0f = (float)y0c, y1f = (float)y1c;

    const float wa = (x1f - x) * (y1f - y);
    const float wb = (x1f - x) * (y - y0f);
    const float wc = (x - x0f) * (y1f - y);
    const float wd = (x - x0f) * (y - y0f);

    // Both corners of a row are adjacent texels (x1c == x0c+1 whenever the
    // clamp doesn't bind); fetch each row as one 16B + one 8B load. min()
    // keeps the tail access in-bounds.
    int oA = (y0c * WDIM + x0c) * 3;
    int oB = (y1c * WDIM + x0c) * 3;
    oA = min(oA, KTOT - 6);
    oB = min(oB, KTOT - 6);
    const float4u Ar  = *(const float4u*)(base + oA);      // a0 a1 a2 c0
    const float2u Ar2 = *(const float2u*)(base + oA + 4);  // c1 c2
    const float4u Br  = *(const float4u*)(base + oB);      // b0 b1 b2 d0
    const float2u Br2 = *(const float2u*)(base + oB + 4);  // d1 d2

    const float r0 = wa * Ar.x + wb * Br.x + wc * Ar.w  + wd * Br.w;
    const float r1 = wa * Ar.y + wb * Br.y + wc * Ar2.x + wd * Br2.x;
    const float r2 = wa * Ar.z + wb * Br.z + wc * Ar2.y + wd * Br2.y;

    float* po = out + (size_t)b * KTOT + (size_t)pix * 3;
    float2u rv; rv.x = r0; rv.y = r1;
    *(float2u*)po = rv;
    po[2] = r2;
}

extern "C" void kernel_launch(void* const* d_in, const int* in_sizes, int n_in,
                              void* d_out, int out_size, void* d_ws, size_t ws_size,
                              hipStream_t stream) {
    const float* inputs = (const float*)d_in[0];
    const float* w1     = (const float*)d_in[1];
    const float* b1     = (const float*)d_in[2];
    const float* w2     = (const float*)d_in[3];
    const float* b2     = (const float*)d_in[4];
    float* out = (float*)d_out;

    float* hacc = (float*)d_ws;                  // NSHARD * 2048 floats
    float* part = (float*)((char*)d_ws + HACC_BYTES);
    const bool two_stage = ws_size >= HACC_BYTES + PART_BYTES;

    if (two_stage) {
        // k2 writes all 16 shards -> no memset, no atomics anywhere.
        k1_gemm<<<NBLK1, 256, 0, stream>>>(inputs, w1, hacc, part);
        k2_reduce<<<512, 256, 0, stream>>>(part, hacc);
    } else {
        hipMemsetAsync(hacc, 0, HACC_BYTES, stream);
        k1_gemm<<<NBLK1, 256, 0, stream>>>(inputs, w1, hacc, (float*)nullptr);
    }
    k3_sample<<<BATCH * BLK3, 1024, 0, stream>>>(inputs, hacc, b1, w2, b2, out);
}

// Round 11
// 134.836 us; speedup vs baseline: 1.3435x; 1.3435x over previous
//
#include <hip/hip_runtime.h>
#include <stdint.h>

#define BATCH 32
#define HDIM 224
#define WDIM 224
#define CDIM 3
#define KTOT (HDIM * WDIM * CDIM)   // 150528
#define HID 64
#define KCHUNK 64
#define NBLK1 (KTOT / KCHUNK)       // 2352
#define PIX (HDIM * WDIM)           // 50176
#define BLK3 49                      // blocks per batch: 1024 thr * 1 px

#define NSHARD 16
#define BH (BATCH * HID)             // 2048
#define HACC_BYTES (NSHARD * BH * 4) // 128 KB
#define PART_BYTES ((size_t)NBLK1 * BH * 4)  // 19.3 MB

typedef float float4v __attribute__((ext_vector_type(4)));
// 4-byte-aligned vector loads (texel addresses are only 4B aligned)
typedef float float4u __attribute__((ext_vector_type(4), aligned(4)));
typedef float float2u __attribute__((ext_vector_type(2), aligned(4)));

// ---------------- Kernel 1: part[blk] = flat @ w1 slice (split-K) -----------
// Round-11 redesign under the measured spill rule: this compiler spills any
// >~52-float live set (r1: asm pins, 192MB scratch; r5: 96 live, 56MB; r10:
// 80 live, 148MB scratch, VGPR=64, k1=72us). Structure: lane = (bh = batch
// octet, hq = hid quad). Per k-quad: 4 w-row b128 reads (2-way alias, free)
// + 8 x b128 reads (bank-disjoint via XOR-rotated columns) -> 12 LDS instrs
// feed 128 FMAs (10.7/instr vs r7's 3.6). Live = acc 32 + w 16 + x 4 = 52.
// Main-loop LDS/wave: 48 instrs (r7: 144) -> per-CU ~10us, near the 9.2us
// HBM floor. Staging stays r7's reg->ds_write (loads feed pre-barrier
// ds_writes -> cannot sink into the FMA loop, the r0/r2 pathology).
// x tile layout: row b at words b*64; column-quad q stored at quad
// ((q + (b>>3)) & 15) -> concurrent bh-group reads hit disjoint bank quads.
__global__ __launch_bounds__(256, 6) void k1_gemm(const float* __restrict__ flat,
                                                  const float* __restrict__ w1,
                                                  float* __restrict__ hacc,
                                                  float* __restrict__ part) {
    __shared__ float smem[6144];                 // 24 KB -> 6 blocks/CU
    const int tid  = threadIdx.x;
    const int lane = tid & 63;
    const int wave = tid >> 6;
    const int k0   = blockIdx.x * KCHUNK;

    // --- Issue all 6 global_load_dwordx4 per thread (pipelined) ---
    // flat: 2 float4 (swizzled dest), w1: 4 float4 (linear dest).
    {
        const int f0 = tid, f1 = tid + 256;      // flat float4 idx 0..511
        const int b0 = f0 >> 4, q0 = f0 & 15;
        const int b1 = f1 >> 4, q1 = f1 & 15;
        const float4v vf0 = *(const float4v*)(flat + (size_t)b0 * KTOT + k0 + q0 * 4);
        const float4v vf1 = *(const float4v*)(flat + (size_t)b1 * KTOT + k0 + q1 * 4);
        const float* wbase = w1 + (size_t)k0 * HID;
        const float4v vw0 = *(const float4v*)(wbase + (size_t)(tid +   0) * 4);
        const float4v vw1 = *(const float4v*)(wbase + (size_t)(tid + 256) * 4);
        const float4v vw2 = *(const float4v*)(wbase + (size_t)(tid + 512) * 4);
        const float4v vw3 = *(const float4v*)(wbase + (size_t)(tid + 768) * 4);
        *(float4v*)(smem + b0 * 64 + ((q0 + (b0 >> 3)) & 15) * 4) = vf0;
        *(float4v*)(smem + b1 * 64 + ((q1 + (b1 >> 3)) & 15) * 4) = vf1;
        *(float4v*)(smem + 2048 + (size_t)(tid +   0) * 4) = vw0;
        *(float4v*)(smem + 2048 + (size_t)(tid + 256) * 4) = vw1;
        *(float4v*)(smem + 2048 + (size_t)(tid + 512) * 4) = vw2;
        *(float4v*)(smem + 2048 + (size_t)(tid + 768) * 4) = vw3;
    }
    __syncthreads();

    const int bh = lane >> 4;                    // batch octet: b = bh*8..+8
    const int hq = lane & 15;                    // hid quad: h = 4hq..4hq+3
    const int wq0 = wave * 4;                    // wave's first k-quad

    float4v acc[8];                              // acc[i][j]: (b=bh*8+i, h=4hq+j)
#pragma unroll
    for (int i = 0; i < 8; ++i) acc[i] = (float4v){0.f, 0.f, 0.f, 0.f};

#pragma unroll
    for (int kkq = 0; kkq < 4; ++kkq) {
        const int qk = wq0 + kkq;                // k-quad 0..15; k = qk*4..+4
        const float4v w0 = *(const float4v*)(smem + 2048 + (qk * 4 + 0) * 64 + hq * 4);
        const float4v w1r = *(const float4v*)(smem + 2048 + (qk * 4 + 1) * 64 + hq * 4);
        const float4v w2r = *(const float4v*)(smem + 2048 + (qk * 4 + 2) * 64 + hq * 4);
        const float4v w3r = *(const float4v*)(smem + 2048 + (qk * 4 + 3) * 64 + hq * 4);
        const int xcol = ((qk + bh) & 15) * 4;   // un-swizzle
#pragma unroll
        for (int i = 0; i < 8; ++i) {
            const float4v x = *(const float4v*)(smem + (bh * 8 + i) * 64 + xcol);
            float4v a = acc[i];
            a.x = fmaf(x.x, w0.x, a.x);  a.y = fmaf(x.x, w0.y, a.y);
            a.z = fmaf(x.x, w0.z, a.z);  a.w = fmaf(x.x, w0.w, a.w);
            a.x = fmaf(x.y, w1r.x, a.x); a.y = fmaf(x.y, w1r.y, a.y);
            a.z = fmaf(x.y, w1r.z, a.z); a.w = fmaf(x.y, w1r.w, a.w);
            a.x = fmaf(x.z, w2r.x, a.x); a.y = fmaf(x.z, w2r.y, a.y);
            a.z = fmaf(x.z, w2r.z, a.z); a.w = fmaf(x.z, w2r.w, a.w);
            a.x = fmaf(x.w, w3r.x, a.x); a.y = fmaf(x.w, w3r.y, a.y);
            a.z = fmaf(x.w, w3r.z, a.z); a.w = fmaf(x.w, w3r.w, a.w);
            acc[i] = a;
        }
    }

    __syncthreads();                             // LDS tiles fully consumed
    // --- Waves 1..3 dump partials (full 24 KB, 8 x b128 each); wave 0 sums --
    if (wave) {
#pragma unroll
        for (int i = 0; i < 8; ++i)
            *(float4v*)(smem + (wave - 1) * 2048 + (bh * 8 + i) * 64 + hq * 4) = acc[i];
    }
    __syncthreads();
    if (wave == 0) {
        if (part) {                              // 2-stage: streaming store
            float* po = part + (size_t)blockIdx.x * BH;
#pragma unroll
            for (int i = 0; i < 8; ++i) {
                const int idx = (bh * 8 + i) * 64 + hq * 4;
                const float4v p0 = *(const float4v*)(smem + idx);
                const float4v p1 = *(const float4v*)(smem + 2048 + idx);
                const float4v p2 = *(const float4v*)(smem + 4096 + idx);
                float4v s = acc[i];
                s.x += p0.x + p1.x + p2.x;
                s.y += p0.y + p1.y + p2.y;
                s.z += p0.z + p1.z + p2.z;
                s.w += p0.w + p1.w + p2.w;
                *(float4v*)(po + idx) = s;
            }
        } else {                                 // fallback: sharded atomics
            float* ha = hacc + (blockIdx.x & (NSHARD - 1)) * BH;
#pragma unroll
            for (int i = 0; i < 8; ++i) {
                const int idx = (bh * 8 + i) * 64 + hq * 4;
                const float4v p0 = *(const float4v*)(smem + idx);
                const float4v p1 = *(const float4v*)(smem + 2048 + idx);
                const float4v p2 = *(const float4v*)(smem + 4096 + idx);
                atomicAdd(ha + idx + 0, acc[i].x + p0.x + p1.x + p2.x);
                atomicAdd(ha + idx + 1, acc[i].y + p0.y + p1.y + p2.y);
                atomicAdd(ha + idx + 2, acc[i].z + p0.z + p1.z + p2.z);
                atomicAdd(ha + idx + 3, acc[i].w + p0.w + p1.w + p2.w);
            }
        }
    }
}

// -------- Kernel 2 (2-stage mode): reduce 2352 partials -> 16 shards --------
// r7 form VERBATIM: 512 blocks (2/CU), each owns shard slot hacc[q][b][*]
// (q<16, 147 rows each). Plain coalesced reads + plain store: zero atomics,
// zero memset. k3 sums the 16 shards.
__global__ __launch_bounds__(256) void k2_reduce(const float* __restrict__ part,
                                                 float* __restrict__ hacc) {
    const int b    = blockIdx.x >> 4;            // 0..31
    const int q    = blockIdx.x & 15;            // 0..15
    const int tid  = threadIdx.x;
    const int lane = tid & 63;
    const int wave = tid >> 6;
    const int r0   = q * 147;

    float s = 0.0f;
    for (int r = r0 + wave; r < r0 + 147; r += 4)
        s += part[(size_t)r * BH + b * HID + lane];

    __shared__ float red[3][64];
    if (wave) red[wave - 1][lane] = s;
    __syncthreads();
    if (wave == 0)
        hacc[q * BH + b * HID + lane] =
            s + red[0][lane] + red[1][lane] + red[2][lane];
}

// -------- Kernel 3: head + affine grid + bilinear sampling ------------------
// r4/r6/r7 form VERBATIM.
__global__ __launch_bounds__(1024) void k3_sample(const float* __restrict__ img,
                                                  const float* __restrict__ hacc,
                                                  const float* __restrict__ b1,
                                                  const float* __restrict__ w2,
                                                  const float* __restrict__ b2,
                                                  float* __restrict__ out) {
    const int b     = blockIdx.x / BLK3;
    const int strip = blockIdx.x - b * BLK3;
    const int tid   = threadIdx.x;
    const int lane  = tid & 63;

    __shared__ float sth[6];
    if (tid < 64) {                              // wave 0: lane = hid
        float a = 0.0f;
#pragma unroll
        for (int s = 0; s < NSHARD; ++s)
            a += hacc[s * BH + b * HID + lane];
        const float hv = tanhf(a + b1[lane]);
        const float* w2p = w2 + lane * 6;        // w2 is [HID][6] row-major
        float q[6];
#pragma unroll
        for (int t = 0; t < 6; ++t) q[t] = hv * w2p[t];
#pragma unroll
        for (int off = 32; off >= 1; off >>= 1) {
#pragma unroll
            for (int t = 0; t < 6; ++t) q[t] += __shfl_xor(q[t], off);
        }
        if (lane < 6) sth[lane] = tanhf(q[lane] + b2[lane]);
    }
    __syncthreads();

    const float t0 = sth[0], t1 = sth[1], t2 = sth[2];
    const float t3 = sth[3], t4 = sth[4], t5 = sth[5];

    const float* base = img + (size_t)b * KTOT;
    const int pix = strip * 1024 + tid;
    const int i   = pix / WDIM;
    const int j   = pix - i * WDIM;

    const float xt = (2.0f * (float)j - (float)(WDIM - 1)) / (float)(WDIM - 1);
    const float yt = (2.0f * (float)i - (float)(HDIM - 1)) / (float)(HDIM - 1);

    const float xs = t0 * xt + t1 * yt + t2;
    const float ys = t3 * xt + t4 * yt + t5;

    const float x = 0.5f * (xs + 1.0f) * (float)(WDIM - 1);
    const float y = 0.5f * (ys + 1.0f) * (float)(HDIM - 1);

    const int x0 = (int)floorf(x);
    const int y0 = (int)floorf(y);

    const int x0c = min(max(x0, 0), WDIM - 1);
    const int x1c = min(max(x0 + 1, 0), WDIM - 1);
    const int y0c = min(max(y0, 0), HDIM - 1);
    const int y1c = min(max(y0 + 1, 0), HDIM - 1);

    // Reference computes weights from CLIPPED corner coordinates.
    const float x0f = (float)x0c, x1f = (float)x1c;
    const float y0f = (float)y0c, y1f = (float)y1c;

    const float wa = (x1f - x) * (y1f - y);
    const float wb = (x1f - x) * (y - y0f);
    const float wc = (x - x0f) * (y1f - y);
    const float wd = (x - x0f) * (y - y0f);

    // Both corners of a row are adjacent texels (x1c == x0c+1 whenever the
    // clamp doesn't bind); fetch each row as one 16B + one 8B load. min()
    // keeps the tail access in-bounds.
    int oA = (y0c * WDIM + x0c) * 3;
    int oB = (y1c * WDIM + x0c) * 3;
    oA = min(oA, KTOT - 6);
    oB = min(oB, KTOT - 6);
    const float4u Ar  = *(const float4u*)(base + oA);      // a0 a1 a2 c0
    const float2u Ar2 = *(const float2u*)(base + oA + 4);  // c1 c2
    const float4u Br  = *(const float4u*)(base + oB);      // b0 b1 b2 d0
    const float2u Br2 = *(const float2u*)(base + oB + 4);  // d1 d2

    const float r0 = wa * Ar.x + wb * Br.x + wc * Ar.w  + wd * Br.w;
    const float r1 = wa * Ar.y + wb * Br.y + wc * Ar2.x + wd * Br2.x;
    const float r2 = wa * Ar.z + wb * Br.z + wc * Ar2.y + wd * Br2.y;

    float* po = out + (size_t)b * KTOT + (size_t)pix * 3;
    float2u rv; rv.x = r0; rv.y = r1;
    *(float2u*)po = rv;
    po[2] = r2;
}

extern "C" void kernel_launch(void* const* d_in, const int* in_sizes, int n_in,
                              void* d_out, int out_size, void* d_ws, size_t ws_size,
                              hipStream_t stream) {
    const float* inputs = (const float*)d_in[0];
    const float* w1     = (const float*)d_in[1];
    const float* b1     = (const float*)d_in[2];
    const float* w2     = (const float*)d_in[3];
    const float* b2     = (const float*)d_in[4];
    float* out = (float*)d_out;

    float* hacc = (float*)d_ws;                  // NSHARD * 2048 floats
    float* part = (float*)((char*)d_ws + HACC_BYTES);
    const bool two_stage = ws_size >= HACC_BYTES + PART_BYTES;

    if (two_stage) {
        // k2 writes all 16 shards -> no memset, no atomics anywhere.
        k1_gemm<<<NBLK1, 256, 0, stream>>>(inputs, w1, hacc, part);
        k2_reduce<<<512, 256, 0, stream>>>(part, hacc);
    } else {
        hipMemsetAsync(hacc, 0, HACC_BYTES, stream);
        k1_gemm<<<NBLK1, 256, 0, stream>>>(inputs, w1, hacc, (float*)nullptr);
    }
    k3_sample<<<BATCH * BLK3, 1024, 0, stream>>>(inputs, hacc, b1, w2, b2, out);
}